// Round 6
// baseline (639.725 us; speedup 1.0000x reference)
//
#include <hip/hip_runtime.h>
#include <stdint.h>

#define TT 2048
#define DD 2048
#define NHH 16
#define HDD 128
#define BTT 4096   // B*T

typedef __attribute__((ext_vector_type(8))) short bf16x8;
typedef __attribute__((ext_vector_type(4))) float f32x4;

// hardware exp2 (v_exp_f32 computes 2^x) — avoids glibc __exp2f macro collision
#define EXP2F(x) __builtin_amdgcn_exp2f(x)

__device__ __forceinline__ unsigned short f2bf(float f) {
    union { float f; uint32_t u; } v; v.f = f;
    uint32_t u = v.u;
    u += 0x7fffu + ((u >> 16) & 1u);   // RNE
    return (unsigned short)(u >> 16);
}

// async global->LDS, 16B per lane. LDS dest = wave-uniform base + lane*16B.
__device__ __forceinline__ void gld16(const unsigned short* g, unsigned short* l) {
    __builtin_amdgcn_global_load_lds(
        (const __attribute__((address_space(1))) unsigned int*)g,
        (__attribute__((address_space(3))) unsigned int*)l, 16, 0, 0);
}

// ---------------- weight fp32 -> bf16 cast ----------------
__global__ __launch_bounds__(256) void convert_w(const float* __restrict__ wq,
                                                 const float* __restrict__ wk,
                                                 const float* __restrict__ wv,
                                                 const float* __restrict__ wo,
                                                 unsigned short* __restrict__ out) {
    size_t gid = (size_t)blockIdx.x * 256 + threadIdx.x;
    size_t base = gid * 8;
    int which = (int)(base >> 22);
    const float* src = which == 0 ? wq : which == 1 ? wk : which == 2 ? wv : wo;
    size_t off = base & 4194303u;
    float4 a = ((const float4*)(src + off))[0];
    float4 b = ((const float4*)(src + off))[1];
    union { unsigned short us[8]; uint4 v; } pk;
    pk.us[0] = f2bf(a.x); pk.us[1] = f2bf(a.y); pk.us[2] = f2bf(a.z); pk.us[3] = f2bf(a.w);
    pk.us[4] = f2bf(b.x); pk.us[5] = f2bf(b.y); pk.us[6] = f2bf(b.z); pk.us[7] = f2bf(b.w);
    *(uint4*)(out + base) = pk.v;
}

// ---------------- RMSNorm fp32 -> bf16 ----------------
__global__ __launch_bounds__(256) void rmsnorm_k(const float* __restrict__ x,
                                                 const float* __restrict__ w,
                                                 unsigned short* __restrict__ xn) {
    const int row = blockIdx.x;
    const int tid = threadIdx.x;
    const float* xr = x + (size_t)row * DD;
    float4 a = ((const float4*)xr)[tid * 2];
    float4 b = ((const float4*)xr)[tid * 2 + 1];
    float ss = a.x*a.x + a.y*a.y + a.z*a.z + a.w*a.w
             + b.x*b.x + b.y*b.y + b.z*b.z + b.w*b.w;
    #pragma unroll
    for (int m = 1; m < 64; m <<= 1) ss += __shfl_xor(ss, m, 64);
    __shared__ float wss[4];
    if ((tid & 63) == 0) wss[tid >> 6] = ss;
    __syncthreads();
    float total = wss[0] + wss[1] + wss[2] + wss[3];
    float norm = sqrtf(total) * 0.022097086912079612f;
    float inv = 1.0f / (norm + 1e-8f);
    float4 wa = ((const float4*)w)[tid * 2];
    float4 wb = ((const float4*)w)[tid * 2 + 1];
    union { unsigned short us[8]; uint4 v; } pk;
    pk.us[0] = f2bf(wa.x * a.x * inv); pk.us[1] = f2bf(wa.y * a.y * inv);
    pk.us[2] = f2bf(wa.z * a.z * inv); pk.us[3] = f2bf(wa.w * a.w * inv);
    pk.us[4] = f2bf(wb.x * b.x * inv); pk.us[5] = f2bf(wb.y * b.y * inv);
    pk.us[6] = f2bf(wb.z * b.z * inv); pk.us[7] = f2bf(wb.w * b.w * inv);
    ((uint4*)(xn + (size_t)row * DD))[tid] = pk.v;
}

// ---------------- m97-style GEMM core: 128x128 tile, BK=32, global_load_lds ----------------
__device__ __forceinline__ void gemm_core(const unsigned short* __restrict__ Ag0,
                                          const unsigned short* __restrict__ Bg0,
                                          unsigned short* As, unsigned short* Bs,
                                          int tid, f32x4 acc[4][4]) {
    const int w = tid >> 6, lane = tid & 63;
    const int l15 = lane & 15, lq = lane >> 4;
    const int wr = (w >> 1) * 64, wc = (w & 1) * 64;
    const unsigned short* ag = Ag0 + (size_t)(w * 16 + (lane >> 2)) * DD + (lane & 3) * 8;
    const unsigned short* bg = Bg0 + (size_t)(w * 16 + (lane >> 2)) * DD + (lane & 3) * 8;
    unsigned short* al = As + w * 512;
    unsigned short* bl = Bs + w * 512;
    for (int k0 = 0; k0 < DD; k0 += 32) {
        __syncthreads();
        gld16(ag + k0, al);
        gld16(ag + k0 + (size_t)64 * DD, al + 64 * 32);
        gld16(bg + k0, bl);
        gld16(bg + k0 + (size_t)64 * DD, bl + 64 * 32);
        __syncthreads();
        bf16x8 af[4], bfr[4];
        #pragma unroll
        for (int i = 0; i < 4; i++)
            af[i] = *(const bf16x8*)(As + (wr + i * 16 + l15) * 32 + lq * 8);
        #pragma unroll
        for (int j = 0; j < 4; j++)
            bfr[j] = *(const bf16x8*)(Bs + (wc + j * 16 + l15) * 32 + lq * 8);
        #pragma unroll
        for (int i = 0; i < 4; i++)
            #pragma unroll
            for (int j = 0; j < 4; j++)
                acc[i][j] = __builtin_amdgcn_mfma_f32_16x16x32_bf16(af[i], bfr[j], acc[i][j], 0, 0, 0);
    }
}

// fused QKV: grid (32, 48): y>>4 selects {wq,wk,wv}. V (which==2) written TRANSPOSED
// [col 0..2047][bt 0..4095] so attention reads B-fragments straight from global.
__global__ __launch_bounds__(256) void gemm_qkv(const unsigned short* __restrict__ A,
                                                const unsigned short* __restrict__ W3,
                                                unsigned short* __restrict__ O3) {
    __shared__ __align__(16) unsigned short As[128 * 32];
    __shared__ __align__(16) unsigned short Bs[128 * 32];
    const int tid = threadIdx.x;
    const int wave = tid >> 6, lane = tid & 63;
    const int l15 = lane & 15, lq = lane >> 4;
    const int by = blockIdx.y;
    const int which = by >> 4;
    const unsigned short* Bw = W3 + (size_t)which * DD * DD;
    unsigned short* C = O3 + (size_t)which * BTT * DD;
    const int m0 = blockIdx.x * 128, n0 = (by & 15) * 128;
    const int wr = (wave >> 1) * 64, wc = (wave & 1) * 64;
    const f32x4 zf = {0.f, 0.f, 0.f, 0.f};
    f32x4 acc[4][4];
    #pragma unroll
    for (int i = 0; i < 4; i++)
        #pragma unroll
        for (int j = 0; j < 4; j++) acc[i][j] = zf;
    gemm_core(A + (size_t)m0 * DD, Bw + (size_t)n0 * DD, As, Bs, tid, acc);
    if (which == 2) {
        // V^T: element (col, row) -> C[col*BTT + row]; r=0..3 rows pack to ushort4
        #pragma unroll
        for (int i = 0; i < 4; i++) {
            const int row = m0 + wr + i * 16 + lq * 4;
            #pragma unroll
            for (int j = 0; j < 4; j++) {
                const int col = n0 + wc + j * 16 + l15;
                ushort4 pk;
                pk.x = f2bf(acc[i][j][0]); pk.y = f2bf(acc[i][j][1]);
                pk.z = f2bf(acc[i][j][2]); pk.w = f2bf(acc[i][j][3]);
                *(ushort4*)(C + (size_t)col * BTT + row) = pk;
            }
        }
    } else {
        #pragma unroll
        for (int i = 0; i < 4; i++) {
            const int row = m0 + wr + i * 16 + lq * 4;
            #pragma unroll
            for (int j = 0; j < 4; j++) {
                const int col = n0 + wc + j * 16 + l15;
                #pragma unroll
                for (int r = 0; r < 4; r++)
                    C[(size_t)(row + r) * DD + col] = f2bf(acc[i][j][r]);
            }
        }
    }
}

// final proj, fp32 out: grid (32, 16)
__global__ __launch_bounds__(256) void gemm_out(const unsigned short* __restrict__ A,
                                                const unsigned short* __restrict__ Bw,
                                                float* __restrict__ C) {
    __shared__ __align__(16) unsigned short As[128 * 32];
    __shared__ __align__(16) unsigned short Bs[128 * 32];
    const int tid = threadIdx.x;
    const int wave = tid >> 6, lane = tid & 63;
    const int l15 = lane & 15, lq = lane >> 4;
    const int m0 = blockIdx.x * 128, n0 = blockIdx.y * 128;
    const int wr = (wave >> 1) * 64, wc = (wave & 1) * 64;
    const f32x4 zf = {0.f, 0.f, 0.f, 0.f};
    f32x4 acc[4][4];
    #pragma unroll
    for (int i = 0; i < 4; i++)
        #pragma unroll
        for (int j = 0; j < 4; j++) acc[i][j] = zf;
    gemm_core(A + (size_t)m0 * DD, Bw + (size_t)n0 * DD, As, Bs, tid, acc);
    #pragma unroll
    for (int i = 0; i < 4; i++) {
        const int row = m0 + wr + i * 16 + lq * 4;
        #pragma unroll
        for (int j = 0; j < 4; j++) {
            const int col = n0 + wc + j * 16 + l15;
            #pragma unroll
            for (int r = 0; r < 4; r++)
                C[(size_t)(row + r) * DD + col] = acc[i][j][r];
        }
    }
}

// ---------------- barrier-free one-wave flash attention, XCD-swizzled ----------------
// 4096 linear blocks x 64 threads (1 wave). Decode: xcd c = id&7, rank = (id>>3)&127,
// s = id>>10; (b,h) group g = s*8+c  -> all 128 q-tiles of one (b,h) share id%8 and
// (under round-robin block->XCD) land on ONE XCD: per-XCD K/V working set 4 MB = L2.
// qj = 127-rank (LPT: long q-tiles dispatched first on every XCD simultaneously).
// K and V^T B-fragments read directly from global (L2-resident); P round-trips
// through 2.8KB wave-private LDS; no __syncthreads.
__global__ __launch_bounds__(64, 4) void attn_wave(const unsigned short* __restrict__ q,
                                                   const unsigned short* __restrict__ k,
                                                   const unsigned short* __restrict__ vt,
                                                   unsigned short* __restrict__ o) {
    constexpr int LPP = 88;  // P row stride (shorts): ~2-way banks on b128 read
    __shared__ __align__(16) unsigned short Ps[16 * LPP];
    const int id = blockIdx.x;
    const int g = (id >> 10) * 8 + (id & 7);     // (b,h) group 0..31
    const int qj = 127 - ((id >> 3) & 127);      // LPT
    const int b = g >> 4, h = g & 15;
    const int lane = threadIdx.x & 63;
    const int l15 = lane & 15, lq = lane >> 4;
    const size_t rowbase = (size_t)b * TT;
    const int hcol = h * HDD;
    const float C2 = 0.1275174458f;  // HD^-0.5 * log2(e)
    const f32x4 zf = {0.f, 0.f, 0.f, 0.f};

    const int qt0 = qj * 16;
    bf16x8 aq[4];
    {
        const unsigned short* qrp = q + (rowbase + qt0 + l15) * DD + hcol;
        #pragma unroll
        for (int kk = 0; kk < 4; kk++)
            aq[kk] = *(const bf16x8*)(qrp + kk * 32 + lq * 8);
    }
    f32x4 acc_o[8];
    #pragma unroll
    for (int jh = 0; jh < 8; jh++) acc_o[jh] = zf;
    float m_i[4], l_i[4];
    #pragma unroll
    for (int r = 0; r < 4; r++) { m_i[r] = -3e37f; l_i[r] = 0.f; }
    const int qp0 = qt0 + lq * 4;
    const int nkt = (qj >> 2) + 1;

    for (int kt = 0; kt < nkt; kt++) {
        const int kbase = kt * 64;
        // S = Q K^T : B-fragments straight from global K[btpos][hd]
        const unsigned short* kg = k + (rowbase + kbase) * DD + hcol;
        bf16x8 bk[4][4];
        #pragma unroll
        for (int j = 0; j < 4; j++)
            #pragma unroll
            for (int kk = 0; kk < 4; kk++)
                bk[j][kk] = *(const bf16x8*)(kg + (size_t)(j * 16 + l15) * DD + kk * 32 + lq * 8);
        f32x4 accs[4];
        #pragma unroll
        for (int j = 0; j < 4; j++) accs[j] = zf;
        #pragma unroll
        for (int j = 0; j < 4; j++)
            #pragma unroll
            for (int kk = 0; kk < 4; kk++)
                accs[j] = __builtin_amdgcn_mfma_f32_16x16x32_bf16(aq[kk], bk[j][kk], accs[j], 0, 0, 0);
        // V^T B-fragments straight from global vt[col][btpos] (issued early)
        const unsigned short* vg = vt + (size_t)hcol * BTT + rowbase + kbase;
        bf16x8 bv[8][2];
        #pragma unroll
        for (int jh = 0; jh < 8; jh++)
            #pragma unroll
            for (int kk = 0; kk < 2; kk++)
                bv[jh][kk] = *(const bf16x8*)(vg + (size_t)(jh * 16 + l15) * BTT + kk * 32 + lq * 8);
        if (kt == nkt - 1) {   // only the last k-tile can cross the diagonal
            #pragma unroll
            for (int j = 0; j < 4; j++) {
                const int kp = kbase + j * 16 + l15;
                #pragma unroll
                for (int r = 0; r < 4; r++)
                    if (kp > qp0 + r) accs[j][r] = -3e37f;
            }
        }
        float rowmax[4] = {-3e37f, -3e37f, -3e37f, -3e37f};
        #pragma unroll
        for (int j = 0; j < 4; j++)
            #pragma unroll
            for (int r = 0; r < 4; r++) rowmax[r] = fmaxf(rowmax[r], accs[j][r]);
        #pragma unroll
        for (int r = 0; r < 4; r++) {
            float mx = rowmax[r];
            mx = fmaxf(mx, __shfl_xor(mx, 1, 64));
            mx = fmaxf(mx, __shfl_xor(mx, 2, 64));
            mx = fmaxf(mx, __shfl_xor(mx, 4, 64));
            mx = fmaxf(mx, __shfl_xor(mx, 8, 64));
            float m_new = fmaxf(m_i[r], mx);
            float al = EXP2F((m_i[r] - m_new) * C2);
            m_i[r] = m_new;
            l_i[r] *= al;
            #pragma unroll
            for (int jh = 0; jh < 8; jh++) acc_o[jh][r] *= al;
        }
        // P = exp2(C2*(S-m)) -> wave-private LDS (C-layout -> A-layout)
        float rowsum[4] = {0.f, 0.f, 0.f, 0.f};
        #pragma unroll
        for (int j = 0; j < 4; j++)
            #pragma unroll
            for (int r = 0; r < 4; r++) {
                float p = EXP2F((accs[j][r] - m_i[r]) * C2);
                rowsum[r] += p;
                Ps[(lq * 4 + r) * LPP + j * 16 + l15] = f2bf(p);
            }
        #pragma unroll
        for (int r = 0; r < 4; r++) {
            float s = rowsum[r];
            s += __shfl_xor(s, 1, 64);
            s += __shfl_xor(s, 2, 64);
            s += __shfl_xor(s, 4, 64);
            s += __shfl_xor(s, 8, 64);
            l_i[r] += s;
        }
        bf16x8 ap[2];
        #pragma unroll
        for (int kk = 0; kk < 2; kk++)
            ap[kk] = *(const bf16x8*)(&Ps[l15 * LPP + kk * 32 + lq * 8]);
        #pragma unroll
        for (int jh = 0; jh < 8; jh++)
            #pragma unroll
            for (int kk = 0; kk < 2; kk++)
                acc_o[jh] = __builtin_amdgcn_mfma_f32_16x16x32_bf16(ap[kk], bv[jh][kk], acc_o[jh], 0, 0, 0);
    }
    // epilogue: O / l
    #pragma unroll
    for (int jh = 0; jh < 8; jh++) {
        const int col = hcol + jh * 16 + l15;
        #pragma unroll
        for (int r = 0; r < 4; r++)
            o[(rowbase + qp0 + r) * DD + col] = f2bf(acc_o[jh][r] * (1.0f / l_i[r]));
    }
}

extern "C" void kernel_launch(void* const* d_in, const int* in_sizes, int n_in,
                              void* d_out, int out_size, void* d_ws, size_t ws_size,
                              hipStream_t stream) {
    const float* x      = (const float*)d_in[0];
    // d_in[1] = attn_mask: deterministic causal tril -> handled analytically
    const float* w_norm = (const float*)d_in[2];
    const float* wq     = (const float*)d_in[3];
    const float* wk     = (const float*)d_in[4];
    const float* wv     = (const float*)d_in[5];
    const float* wo     = (const float*)d_in[6];

    unsigned short* wbf = (unsigned short*)d_ws;                 // [4][D*D]
    unsigned short* xn  = wbf + (size_t)4 * DD * DD;             // [BT][D]
    unsigned short* qb  = xn + (size_t)BTT * DD;
    unsigned short* kb  = qb + (size_t)BTT * DD;
    unsigned short* vb  = kb + (size_t)BTT * DD;                 // holds V^T [col][bt]
    unsigned short* ab  = vb + (size_t)BTT * DD;

    convert_w<<<8192, 256, 0, stream>>>(wq, wk, wv, wo, wbf);
    rmsnorm_k<<<BTT, 256, 0, stream>>>(x, w_norm, xn);
    dim3 gqkv(32, 48);
    gemm_qkv<<<gqkv, 256, 0, stream>>>(xn, wbf, qb);
    attn_wave<<<4096, 64, 0, stream>>>(qb, kb, vb, ab);
    dim3 gout(32, 16);
    gemm_out<<<gout, 256, 0, stream>>>(ab, wbf + (size_t)3 * DD * DD, (float*)d_out);
}

// Round 7
// 586.938 us; speedup vs baseline: 1.0899x; 1.0899x over previous
//
#include <hip/hip_runtime.h>
#include <stdint.h>

#define TT 2048
#define DD 2048
#define NHH 16
#define HDD 128
#define BTT 4096   // B*T

typedef __attribute__((ext_vector_type(8))) short bf16x8;
typedef __attribute__((ext_vector_type(4))) float f32x4;

// hardware exp2 (v_exp_f32 computes 2^x) — avoids glibc __exp2f macro collision
#define EXP2F(x) __builtin_amdgcn_exp2f(x)

__device__ __forceinline__ unsigned short f2bf(float f) {
    union { float f; uint32_t u; } v; v.f = f;
    uint32_t u = v.u;
    u += 0x7fffu + ((u >> 16) & 1u);   // RNE
    return (unsigned short)(u >> 16);
}

// async global->LDS, 16B per lane. LDS dest = wave-uniform base + lane*16B.
__device__ __forceinline__ void gld16(const unsigned short* g, unsigned short* l) {
    __builtin_amdgcn_global_load_lds(
        (const __attribute__((address_space(1))) unsigned int*)g,
        (__attribute__((address_space(3))) unsigned int*)l, 16, 0, 0);
}

// ---------------- weight fp32 -> bf16 cast ----------------
__global__ __launch_bounds__(256) void convert_w(const float* __restrict__ wq,
                                                 const float* __restrict__ wk,
                                                 const float* __restrict__ wv,
                                                 const float* __restrict__ wo,
                                                 unsigned short* __restrict__ out) {
    size_t gid = (size_t)blockIdx.x * 256 + threadIdx.x;
    size_t base = gid * 8;
    int which = (int)(base >> 22);
    const float* src = which == 0 ? wq : which == 1 ? wk : which == 2 ? wv : wo;
    size_t off = base & 4194303u;
    float4 a = ((const float4*)(src + off))[0];
    float4 b = ((const float4*)(src + off))[1];
    union { unsigned short us[8]; uint4 v; } pk;
    pk.us[0] = f2bf(a.x); pk.us[1] = f2bf(a.y); pk.us[2] = f2bf(a.z); pk.us[3] = f2bf(a.w);
    pk.us[4] = f2bf(b.x); pk.us[5] = f2bf(b.y); pk.us[6] = f2bf(b.z); pk.us[7] = f2bf(b.w);
    *(uint4*)(out + base) = pk.v;
}

// ---------------- RMSNorm fp32 -> bf16 ----------------
__global__ __launch_bounds__(256) void rmsnorm_k(const float* __restrict__ x,
                                                 const float* __restrict__ w,
                                                 unsigned short* __restrict__ xn) {
    const int row = blockIdx.x;
    const int tid = threadIdx.x;
    const float* xr = x + (size_t)row * DD;
    float4 a = ((const float4*)xr)[tid * 2];
    float4 b = ((const float4*)xr)[tid * 2 + 1];
    float ss = a.x*a.x + a.y*a.y + a.z*a.z + a.w*a.w
             + b.x*b.x + b.y*b.y + b.z*b.z + b.w*b.w;
    #pragma unroll
    for (int m = 1; m < 64; m <<= 1) ss += __shfl_xor(ss, m, 64);
    __shared__ float wss[4];
    if ((tid & 63) == 0) wss[tid >> 6] = ss;
    __syncthreads();
    float total = wss[0] + wss[1] + wss[2] + wss[3];
    float norm = sqrtf(total) * 0.022097086912079612f;
    float inv = 1.0f / (norm + 1e-8f);
    float4 wa = ((const float4*)w)[tid * 2];
    float4 wb = ((const float4*)w)[tid * 2 + 1];
    union { unsigned short us[8]; uint4 v; } pk;
    pk.us[0] = f2bf(wa.x * a.x * inv); pk.us[1] = f2bf(wa.y * a.y * inv);
    pk.us[2] = f2bf(wa.z * a.z * inv); pk.us[3] = f2bf(wa.w * a.w * inv);
    pk.us[4] = f2bf(wb.x * b.x * inv); pk.us[5] = f2bf(wb.y * b.y * inv);
    pk.us[6] = f2bf(wb.z * b.z * inv); pk.us[7] = f2bf(wb.w * b.w * inv);
    ((uint4*)(xn + (size_t)row * DD))[tid] = pk.v;
}

// ---------------- m97-style GEMM core: 128x128 tile, BK=32, global_load_lds ----------------
__device__ __forceinline__ void gemm_core(const unsigned short* __restrict__ Ag0,
                                          const unsigned short* __restrict__ Bg0,
                                          unsigned short* As, unsigned short* Bs,
                                          int tid, f32x4 acc[4][4]) {
    const int w = tid >> 6, lane = tid & 63;
    const int l15 = lane & 15, lq = lane >> 4;
    const int wr = (w >> 1) * 64, wc = (w & 1) * 64;
    const unsigned short* ag = Ag0 + (size_t)(w * 16 + (lane >> 2)) * DD + (lane & 3) * 8;
    const unsigned short* bg = Bg0 + (size_t)(w * 16 + (lane >> 2)) * DD + (lane & 3) * 8;
    unsigned short* al = As + w * 512;
    unsigned short* bl = Bs + w * 512;
    for (int k0 = 0; k0 < DD; k0 += 32) {
        __syncthreads();
        gld16(ag + k0, al);
        gld16(ag + k0 + (size_t)64 * DD, al + 64 * 32);
        gld16(bg + k0, bl);
        gld16(bg + k0 + (size_t)64 * DD, bl + 64 * 32);
        __syncthreads();
        bf16x8 af[4], bfr[4];
        #pragma unroll
        for (int i = 0; i < 4; i++)
            af[i] = *(const bf16x8*)(As + (wr + i * 16 + l15) * 32 + lq * 8);
        #pragma unroll
        for (int j = 0; j < 4; j++)
            bfr[j] = *(const bf16x8*)(Bs + (wc + j * 16 + l15) * 32 + lq * 8);
        #pragma unroll
        for (int i = 0; i < 4; i++)
            #pragma unroll
            for (int j = 0; j < 4; j++)
                acc[i][j] = __builtin_amdgcn_mfma_f32_16x16x32_bf16(af[i], bfr[j], acc[i][j], 0, 0, 0);
    }
}

// fused QKV: grid (32, 48): y>>4 selects {wq,wk,wv}. V (which==2) written TRANSPOSED
// [col 0..2047][bt 0..4095] so attention reads B-fragments straight from global.
__global__ __launch_bounds__(256) void gemm_qkv(const unsigned short* __restrict__ A,
                                                const unsigned short* __restrict__ W3,
                                                unsigned short* __restrict__ O3) {
    __shared__ __align__(16) unsigned short As[128 * 32];
    __shared__ __align__(16) unsigned short Bs[128 * 32];
    const int tid = threadIdx.x;
    const int wave = tid >> 6, lane = tid & 63;
    const int l15 = lane & 15, lq = lane >> 4;
    const int by = blockIdx.y;
    const int which = by >> 4;
    const unsigned short* Bw = W3 + (size_t)which * DD * DD;
    unsigned short* C = O3 + (size_t)which * BTT * DD;
    const int m0 = blockIdx.x * 128, n0 = (by & 15) * 128;
    const int wr = (wave >> 1) * 64, wc = (wave & 1) * 64;
    const f32x4 zf = {0.f, 0.f, 0.f, 0.f};
    f32x4 acc[4][4];
    #pragma unroll
    for (int i = 0; i < 4; i++)
        #pragma unroll
        for (int j = 0; j < 4; j++) acc[i][j] = zf;
    gemm_core(A + (size_t)m0 * DD, Bw + (size_t)n0 * DD, As, Bs, tid, acc);
    if (which == 2) {
        // V^T: element (col, row) -> C[col*BTT + row]; r=0..3 rows pack to ushort4
        #pragma unroll
        for (int i = 0; i < 4; i++) {
            const int row = m0 + wr + i * 16 + lq * 4;
            #pragma unroll
            for (int j = 0; j < 4; j++) {
                const int col = n0 + wc + j * 16 + l15;
                ushort4 pk;
                pk.x = f2bf(acc[i][j][0]); pk.y = f2bf(acc[i][j][1]);
                pk.z = f2bf(acc[i][j][2]); pk.w = f2bf(acc[i][j][3]);
                *(ushort4*)(C + (size_t)col * BTT + row) = pk;
            }
        }
    } else {
        #pragma unroll
        for (int i = 0; i < 4; i++) {
            const int row = m0 + wr + i * 16 + lq * 4;
            #pragma unroll
            for (int j = 0; j < 4; j++) {
                const int col = n0 + wc + j * 16 + l15;
                #pragma unroll
                for (int r = 0; r < 4; r++)
                    C[(size_t)(row + r) * DD + col] = f2bf(acc[i][j][r]);
            }
        }
    }
}

// final proj, fp32 out: grid (32, 16)
__global__ __launch_bounds__(256) void gemm_out(const unsigned short* __restrict__ A,
                                                const unsigned short* __restrict__ Bw,
                                                float* __restrict__ C) {
    __shared__ __align__(16) unsigned short As[128 * 32];
    __shared__ __align__(16) unsigned short Bs[128 * 32];
    const int tid = threadIdx.x;
    const int wave = tid >> 6, lane = tid & 63;
    const int l15 = lane & 15, lq = lane >> 4;
    const int m0 = blockIdx.x * 128, n0 = blockIdx.y * 128;
    const int wr = (wave >> 1) * 64, wc = (wave & 1) * 64;
    const f32x4 zf = {0.f, 0.f, 0.f, 0.f};
    f32x4 acc[4][4];
    #pragma unroll
    for (int i = 0; i < 4; i++)
        #pragma unroll
        for (int j = 0; j < 4; j++) acc[i][j] = zf;
    gemm_core(A + (size_t)m0 * DD, Bw + (size_t)n0 * DD, As, Bs, tid, acc);
    #pragma unroll
    for (int i = 0; i < 4; i++) {
        const int row = m0 + wr + i * 16 + lq * 4;
        #pragma unroll
        for (int j = 0; j < 4; j++) {
            const int col = n0 + wc + j * 16 + l15;
            #pragma unroll
            for (int r = 0; r < 4; r++)
                C[(size_t)(row + r) * DD + col] = acc[i][j][r];
        }
    }
}

// ---------------- barrier-free one-wave flash attention, XCD-swizzled ----------------
// 4096 linear blocks x 64 threads (1 wave). Decode: xcd c = id&7, rank = (id>>3)&127,
// s = id>>10; (b,h) group g = s*8+c  -> all 128 q-tiles of one (b,h) share id%8 and
// (under round-robin block->XCD) land on ONE XCD: per-XCD K/V working set 4 MB = L2.
// qj = 127-rank (LPT). K and V^T B-fragments read directly from global (L2-resident);
// P round-trips through 2.8KB wave-private LDS; no __syncthreads.
// launch_bounds(64,2): keeps ~104 VGPRs -> bk[16]+bv[16] fragments stay in registers
// (NO scratch spill; (64,4) squeezed to 64 VGPRs and spilled -> WRITE_SIZE 46MB, R6).
__global__ __launch_bounds__(64, 2) void attn_wave(const unsigned short* __restrict__ q,
                                                   const unsigned short* __restrict__ k,
                                                   const unsigned short* __restrict__ vt,
                                                   unsigned short* __restrict__ o) {
    constexpr int LPP = 88;  // P row stride (shorts): ~2-way banks on b128 read
    __shared__ __align__(16) unsigned short Ps[16 * LPP];
    const int id = blockIdx.x;
    const int g = (id >> 10) * 8 + (id & 7);     // (b,h) group 0..31
    const int qj = 127 - ((id >> 3) & 127);      // LPT
    const int b = g >> 4, h = g & 15;
    const int lane = threadIdx.x & 63;
    const int l15 = lane & 15, lq = lane >> 4;
    const size_t rowbase = (size_t)b * TT;
    const int hcol = h * HDD;
    const float C2 = 0.1275174458f;  // HD^-0.5 * log2(e)
    const f32x4 zf = {0.f, 0.f, 0.f, 0.f};

    const int qt0 = qj * 16;
    bf16x8 aq[4];
    {
        const unsigned short* qrp = q + (rowbase + qt0 + l15) * DD + hcol;
        #pragma unroll
        for (int kk = 0; kk < 4; kk++)
            aq[kk] = *(const bf16x8*)(qrp + kk * 32 + lq * 8);
    }
    f32x4 acc_o[8];
    #pragma unroll
    for (int jh = 0; jh < 8; jh++) acc_o[jh] = zf;
    float m_i[4], l_i[4];
    #pragma unroll
    for (int r = 0; r < 4; r++) { m_i[r] = -3e37f; l_i[r] = 0.f; }
    const int qp0 = qt0 + lq * 4;
    const int nkt = (qj >> 2) + 1;

    for (int kt = 0; kt < nkt; kt++) {
        const int kbase = kt * 64;
        // S = Q K^T : B-fragments straight from global K[btpos][hd]
        const unsigned short* kg = k + (rowbase + kbase) * DD + hcol;
        bf16x8 bk[4][4];
        #pragma unroll
        for (int j = 0; j < 4; j++)
            #pragma unroll
            for (int kk = 0; kk < 4; kk++)
                bk[j][kk] = *(const bf16x8*)(kg + (size_t)(j * 16 + l15) * DD + kk * 32 + lq * 8);
        f32x4 accs[4];
        #pragma unroll
        for (int j = 0; j < 4; j++) accs[j] = zf;
        #pragma unroll
        for (int j = 0; j < 4; j++)
            #pragma unroll
            for (int kk = 0; kk < 4; kk++)
                accs[j] = __builtin_amdgcn_mfma_f32_16x16x32_bf16(aq[kk], bk[j][kk], accs[j], 0, 0, 0);
        // V^T B-fragments straight from global vt[col][btpos] (issued early)
        const unsigned short* vg = vt + (size_t)hcol * BTT + rowbase + kbase;
        bf16x8 bv[8][2];
        #pragma unroll
        for (int jh = 0; jh < 8; jh++)
            #pragma unroll
            for (int kk = 0; kk < 2; kk++)
                bv[jh][kk] = *(const bf16x8*)(vg + (size_t)(jh * 16 + l15) * BTT + kk * 32 + lq * 8);
        if (kt == nkt - 1) {   // only the last k-tile can cross the diagonal
            #pragma unroll
            for (int j = 0; j < 4; j++) {
                const int kp = kbase + j * 16 + l15;
                #pragma unroll
                for (int r = 0; r < 4; r++)
                    if (kp > qp0 + r) accs[j][r] = -3e37f;
            }
        }
        float rowmax[4] = {-3e37f, -3e37f, -3e37f, -3e37f};
        #pragma unroll
        for (int j = 0; j < 4; j++)
            #pragma unroll
            for (int r = 0; r < 4; r++) rowmax[r] = fmaxf(rowmax[r], accs[j][r]);
        #pragma unroll
        for (int r = 0; r < 4; r++) {
            float mx = rowmax[r];
            mx = fmaxf(mx, __shfl_xor(mx, 1, 64));
            mx = fmaxf(mx, __shfl_xor(mx, 2, 64));
            mx = fmaxf(mx, __shfl_xor(mx, 4, 64));
            mx = fmaxf(mx, __shfl_xor(mx, 8, 64));
            float m_new = fmaxf(m_i[r], mx);
            float al = EXP2F((m_i[r] - m_new) * C2);
            m_i[r] = m_new;
            l_i[r] *= al;
            #pragma unroll
            for (int jh = 0; jh < 8; jh++) acc_o[jh][r] *= al;
        }
        // P = exp2(C2*(S-m)) -> wave-private LDS (C-layout -> A-layout)
        float rowsum[4] = {0.f, 0.f, 0.f, 0.f};
        #pragma unroll
        for (int j = 0; j < 4; j++)
            #pragma unroll
            for (int r = 0; r < 4; r++) {
                float p = EXP2F((accs[j][r] - m_i[r]) * C2);
                rowsum[r] += p;
                Ps[(lq * 4 + r) * LPP + j * 16 + l15] = f2bf(p);
            }
        #pragma unroll
        for (int r = 0; r < 4; r++) {
            float s = rowsum[r];
            s += __shfl_xor(s, 1, 64);
            s += __shfl_xor(s, 2, 64);
            s += __shfl_xor(s, 4, 64);
            s += __shfl_xor(s, 8, 64);
            l_i[r] += s;
        }
        bf16x8 ap[2];
        #pragma unroll
        for (int kk = 0; kk < 2; kk++)
            ap[kk] = *(const bf16x8*)(&Ps[l15 * LPP + kk * 32 + lq * 8]);
        #pragma unroll
        for (int jh = 0; jh < 8; jh++)
            #pragma unroll
            for (int kk = 0; kk < 2; kk++)
                acc_o[jh] = __builtin_amdgcn_mfma_f32_16x16x32_bf16(ap[kk], bv[jh][kk], acc_o[jh], 0, 0, 0);
    }
    // epilogue: O / l
    #pragma unroll
    for (int jh = 0; jh < 8; jh++) {
        const int col = hcol + jh * 16 + l15;
        #pragma unroll
        for (int r = 0; r < 4; r++)
            o[(rowbase + qp0 + r) * DD + col] = f2bf(acc_o[jh][r] * (1.0f / l_i[r]));
    }
}

extern "C" void kernel_launch(void* const* d_in, const int* in_sizes, int n_in,
                              void* d_out, int out_size, void* d_ws, size_t ws_size,
                              hipStream_t stream) {
    const float* x      = (const float*)d_in[0];
    // d_in[1] = attn_mask: deterministic causal tril -> handled analytically
    const float* w_norm = (const float*)d_in[2];
    const float* wq     = (const float*)d_in[3];
    const float* wk     = (const float*)d_in[4];
    const float* wv     = (const float*)d_in[5];
    const float* wo     = (const float*)d_in[6];

    unsigned short* wbf = (unsigned short*)d_ws;                 // [4][D*D]
    unsigned short* xn  = wbf + (size_t)4 * DD * DD;             // [BT][D]
    unsigned short* qb  = xn + (size_t)BTT * DD;
    unsigned short* kb  = qb + (size_t)BTT * DD;
    unsigned short* vb  = kb + (size_t)BTT * DD;                 // holds V^T [col][bt]
    unsigned short* ab  = vb + (size_t)BTT * DD;

    convert_w<<<8192, 256, 0, stream>>>(wq, wk, wv, wo, wbf);
    rmsnorm_k<<<BTT, 256, 0, stream>>>(x, w_norm, xn);
    dim3 gqkv(32, 48);
    gemm_qkv<<<gqkv, 256, 0, stream>>>(xn, wbf, qb);
    attn_wave<<<4096, 64, 0, stream>>>(qb, kb, vb, ab);
    dim3 gout(32, 16);
    gemm_out<<<gout, 256, 0, stream>>>(ab, wbf + (size_t)3 * DD * DD, (float*)d_out);
}